// Round 19
// baseline (521.885 us; speedup 1.0000x reference)
//
#include <hip/hip_runtime.h>

#define DD 64      // input feature dim
#define D2 128     // h1 dim
#define CC 4       // communities / clusters
#define SS 8       // members per community
#define MM 16      // neighbors
#define OUTW 384   // output row width (h1 | h1 | cluster)
#define LDST 132   // padded LDS row stride in floats (16B-aligned float4 reads)
#define NMAX 100000

// Compact h1 copy (128 f32/row, 512B stride): 51.2 MB BSS. Shrinks k2's
// gather pool from 153.6 MB (out, 1536B rows) to 51.2 MB -> L3-resident.
__device__ float g_h1c[(size_t)NMAX * D2];

// ---------------- Layer 1: h1 = relu([x, max_c mean_s feat[comm]]) ----------
// TWO nodes per wave: half = lane>>5, hl = lane&31 owns dims {2hl, 2hl+1}.
// Per-dim FP order (sequential ascending-s adds, *0.125f) -> bit-exact.
template<bool BSS>
__global__ __launch_bounds__(256) void sdgnn_k1(
    const float* __restrict__ feat, const int* __restrict__ comm,
    float* __restrict__ out, int N) {
  #pragma clang fp contract(off)
  int wid = blockIdx.x * 4 + (threadIdx.x >> 6);
  int lane = threadIdx.x & 63;
  int half = lane >> 5, hl = lane & 31;
  int n = wid * 2 + half;
  if (n >= N) return;                      // no barriers in k1: divergence ok
  int cidx = comm[(size_t)n * (CC * SS) + hl];
  float2 x = *(const float2*)(feat + (size_t)n * DD + 2 * hl);
  float2 g = make_float2(0.f, 0.f);
  #pragma unroll
  for (int c = 0; c < CC; ++c) {
    float ax = 0.f, ay = 0.f;
    #pragma unroll
    for (int s = 0; s < SS; ++s) {
      int j = __shfl(cidx, c * SS + s + (half << 5));  // this half's indices
      float2 v = *(const float2*)(feat + (size_t)j * DD + 2 * hl);
      ax = ax + v.x;                       // sequential, ascending s
      ay = ay + v.y;
    }
    ax = ax * 0.125f;                      // /8 exact
    ay = ay * 0.125f;
    g.x = (c == 0) ? ax : fmaxf(g.x, ax);  // max over c, ascending
    g.y = (c == 0) ? ay : fmaxf(g.y, ay);
  }
  float2 h1a = make_float2(fmaxf(x.x, 0.f), fmaxf(x.y, 0.f));
  float2 h1b = make_float2(fmaxf(g.x, 0.f), fmaxf(g.y, 0.f));
  size_t base = (size_t)n * OUTW + 2 * hl;
  *(float2*)(out + base) = h1a;
  *(float2*)(out + base + 64) = h1b;
  *(float2*)(out + base + 128) = h1a;      // h2 first half == h1 (relu(h1)=h1)
  *(float2*)(out + base + 192) = h1b;
  if (BSS) {
    float* p = g_h1c + (size_t)n * D2 + 2 * hl;
    *(float2*)(p) = h1a;                   // compact copy for k2's gathers
    *(float2*)(p + 64) = h1b;
  }
}

// ---------------- Layer 2: 1-step KMeans + scatter-mean + maxpool -----------
// one wave per block. Golden bit-order preserved (W16 chained-FMA dot + W16
// pairwise c2, halves-tree reduces; sequential means; IEEE div; first-min
// argmin). Gathers from the COMPACT h1 pool (512B rows, 51.2MB). Aggregate:
// values from LDS at point of use; selector from wave-uniform ballot masks
// via scalar pipe. Bitwise identical to golden.
template<bool BSS>
__global__ __launch_bounds__(64) void sdgnn_k2(
    const int* __restrict__ comm, const int* __restrict__ neigh,
    float* __restrict__ out, int N) {
  #pragma clang fp contract(off)
  __shared__ __align__(16) float L[(MM + CC) * LDST];
  const int lane = threadIdx.x;
  const int n = blockIdx.x;
  const float* __restrict__ h1 = BSS ? g_h1c : out;
  const size_t HS = BSS ? D2 : OUTW;       // h1 row stride

  const int cidx = comm[(size_t)n * (CC * SS) + (lane & 31)];
  const int nidx = neigh[(size_t)n * MM + (lane & 15)];

  // stage neighbor h1 rows to LDS
  #pragma unroll
  for (int m = 0; m < MM; ++m) {
    int j = __shfl(nidx, m);
    float2 v = *(const float2*)(h1 + (size_t)j * HS + 2 * lane);
    *(float2*)(L + m * LDST + 2 * lane) = v;
  }
  // init centers = mean of 8 member h1 rows: sequential ascending-s adds
  float2 ctr[CC];
  #pragma unroll
  for (int c = 0; c < CC; ++c) {
    float ax = 0.f, ay = 0.f;
    #pragma unroll
    for (int s = 0; s < SS; ++s) {
      int j = __shfl(cidx, c * SS + s);
      float2 v = *(const float2*)(h1 + (size_t)j * HS + 2 * lane);
      ax = ax + v.x;
      ay = ay + v.y;
    }
    ctr[c].x = ax * 0.125f;
    ctr[c].y = ay * 0.125f;
    *(float2*)(L + (MM + c) * LDST + 2 * lane) = ctr[c];
  }
  __syncthreads();

  const int mm = lane >> 2, cc = lane & 3;
  const float4* nrow4 = (const float4*)(L + mm * LDST);
  const float4* crow4 = (const float4*)(L + (MM + cc) * LDST);
  const float* c2row = L + (MM + (lane >> 4)) * LDST;  // c2 row (c = lane>>4)
  const int Lc = lane & 15;

  // c2 cooperative: lane (c,L) computes S[L]; shfl_xor strides 8,4,2,1 equal
  // the halves-tree bitwise (IEEE add commutes).
  auto compute_c2 = [&]() -> float {
    #pragma clang fp contract(off)
    float a0 = c2row[0*16+Lc], a1 = c2row[1*16+Lc], a2 = c2row[2*16+Lc], a3 = c2row[3*16+Lc];
    float a4 = c2row[4*16+Lc], a5 = c2row[5*16+Lc], a6 = c2row[6*16+Lc], a7 = c2row[7*16+Lc];
    float s = ((a0*a0 + a1*a1) + (a2*a2 + a3*a3)) + ((a4*a4 + a5*a5) + (a6*a6 + a7*a7));
    s = s + __shfl_xor(s, 8);
    s = s + __shfl_xor(s, 4);
    s = s + __shfl_xor(s, 2);
    s = s + __shfl_xor(s, 1);
    return __shfl(s, cc << 4);   // c2 of this lane's cluster cc
  };

  // dot: W16 chained-FMA per model-lane, ascending k, halves-tree reduce.
  auto assign_lbl = [&]() -> int {
    #pragma clang fp contract(off)
    float c2 = compute_c2();
    float S[16];
    #pragma unroll
    for (int j = 0; j < 4; ++j) {
      float sx = 0.f, sy = 0.f, sz = 0.f, sw = 0.f;
      #pragma unroll
      for (int k = 0; k < 8; ++k) {
        float4 a = nrow4[k*4+j], b = crow4[k*4+j];
        sx = fmaf(a.x, b.x, sx);
        sy = fmaf(a.y, b.y, sy);
        sz = fmaf(a.z, b.z, sz);
        sw = fmaf(a.w, b.w, sw);
      }
      S[4*j+0] = sx; S[4*j+1] = sy; S[4*j+2] = sz; S[4*j+3] = sw;
    }
    float A0 = S[0] + S[8],  A1 = S[1] + S[9],  A2 = S[2] + S[10], A3 = S[3] + S[11];
    float A4 = S[4] + S[12], A5 = S[5] + S[13], A6 = S[6] + S[14], A7 = S[7] + S[15];
    float B0 = A0 + A4, B1 = A1 + A5, B2 = A2 + A6, B3 = A3 + A7;
    float C0 = B0 + B2, C1 = B1 + B3;
    float dot = C0 + C1;

    float bd = c2 - 2.f * dot;   // 2*dot exact; one rounded subtract
    int bc = cc;
    #pragma unroll
    for (int off = 1; off <= 2; off <<= 1) {
      float od = __shfl_xor(bd, off);
      int oc = __shfl_xor(bc, off);
      if (od < bd || (od == bd && oc < bc)) { bd = od; bc = oc; }
    }
    return bc;  // label of neighbor mm on all 4 group lanes
  };

  // scatter-sum by label, ascending m, values from LDS; selector from the
  // wave-uniform ballot masks (scalar pipe -> SGPR 0/1 operand of v_fmac).
  auto aggregate = [&](int bc, float2 acc[CC], float cnt[CC]) {
    #pragma clang fp contract(off)
    unsigned long long msk[CC];
    #pragma unroll
    for (int c = 0; c < CC; ++c) {
      msk[c] = __ballot(bc == c);                           // wave-uniform SGPR
      acc[c].x = 0.f; acc[c].y = 0.f;
      cnt[c] = (float)__popcll(msk[c] & 0x1111111111111111ULL);  // lanes 4m
    }
    #pragma unroll
    for (int m = 0; m < MM; ++m) {
      float2 v = *(const float2*)(L + m * LDST + 2 * lane);
      #pragma unroll
      for (int c = 0; c < CC; ++c) {
        float sel = __uint_as_float(
            (unsigned)((msk[c] >> (4 * m)) & 1ULL) * 0x3f800000u);  // scalar 0/1
        acc[c].x = fmaf(sel, v.x, acc[c].x);
        acc[c].y = fmaf(sel, v.y, acc[c].y);
      }
    }
  };

  // E-step on init centers, then M-step
  int lbl0 = assign_lbl();
  float2 a0[CC]; float c0[CC];
  aggregate(lbl0, a0, c0);
  float2 ctr1[CC];
  #pragma unroll
  for (int c = 0; c < CC; ++c) {
    float den = fmaxf(c0[c], 1.f);       // maximum(cnt,1.0)
    float mx = a0[c].x / den;            // IEEE f32 divide
    float my = a0[c].y / den;
    ctr1[c].x = (c0[c] > 0.f) ? mx : ctr[c].x;  // where(cnt>0, mean, center)
    ctr1[c].y = (c0[c] > 0.f) ? my : ctr[c].y;
  }
  __syncthreads();  // WAR on center rows (1 wave: cheap)
  #pragma unroll
  for (int c = 0; c < CC; ++c)
    *(float2*)(L + (MM + c) * LDST + 2 * lane) = ctr1[c];
  __syncthreads();

  // final E-step + scatter-mean (empty -> 0) + maxpool + relu
  int lbl1 = assign_lbl();
  float2 a1[CC]; float c1n[CC];
  aggregate(lbl1, a1, c1n);
  float rx = 0.f, ry = 0.f;
  #pragma unroll
  for (int c = 0; c < CC; ++c) {
    float den = fmaxf(c1n[c], 1.f);
    float gx = a1[c].x / den;            // empty: 0/1 = +0
    float gy = a1[c].y / den;
    rx = (c == 0) ? gx : fmaxf(rx, gx);  // max over c, ascending
    ry = (c == 0) ? gy : fmaxf(ry, gy);
  }
  size_t base = (size_t)n * OUTW + 256 + 2 * lane;
  float2 res;
  res.x = fmaxf(rx, 0.f);
  res.y = fmaxf(ry, 0.f);
  *(float2*)(out + base) = res;
}

extern "C" void kernel_launch(void* const* d_in, const int* in_sizes, int n_in,
                              void* d_out, int out_size, void* d_ws, size_t ws_size,
                              hipStream_t stream) {
  const float* feat = (const float*)d_in[0];
  const int* comm = (const int*)d_in[1];
  const int* neigh = (const int*)d_in[2];
  float* out = (float*)d_out;
  const int N = in_sizes[0] / DD;

  int blocks1 = (N + 7) / 8;   // 4 waves/block, 2 nodes per wave
  if (N <= NMAX) {
    sdgnn_k1<true><<<blocks1, 256, 0, stream>>>(feat, comm, out, N);
    sdgnn_k2<true><<<N, 64, 0, stream>>>(comm, neigh, out, N);
  } else {
    sdgnn_k1<false><<<blocks1, 256, 0, stream>>>(feat, comm, out, N);
    sdgnn_k2<false><<<N, 64, 0, stream>>>(comm, neigh, out, N);
  }
}

// Round 20
// 437.304 us; speedup vs baseline: 1.1934x; 1.1934x over previous
//
#include <hip/hip_runtime.h>

#define DD 64      // input feature dim
#define D2 128     // h1 dim
#define CC 4       // communities / clusters
#define SS 8       // members per community
#define MM 16      // neighbors
#define OUTW 384   // output row width (h1 | h1 | cluster)
#define LDST 132   // padded LDS row stride in floats (16B-aligned float4 reads)

// ---------------- Layer 1: h1 = relu([x, max_c mean_s feat[comm]]) ----------
// TWO nodes per wave: half = lane>>5 picks the node, hl = lane&31 owns dims
// {2hl, 2hl+1}. Per-dim FP order (sequential ascending-s adds, *0.125f)
// unchanged -> bit-exact; float2 loads.
__global__ __launch_bounds__(256) void sdgnn_k1(
    const float* __restrict__ feat, const int* __restrict__ comm,
    float* __restrict__ out, int N) {
  #pragma clang fp contract(off)
  int wid = blockIdx.x * 4 + (threadIdx.x >> 6);
  int lane = threadIdx.x & 63;
  int half = lane >> 5, hl = lane & 31;
  int n = wid * 2 + half;
  if (n >= N) return;                      // no barriers in k1: divergence ok
  int cidx = comm[(size_t)n * (CC * SS) + hl];
  float2 x = *(const float2*)(feat + (size_t)n * DD + 2 * hl);
  float2 g = make_float2(0.f, 0.f);
  #pragma unroll
  for (int c = 0; c < CC; ++c) {
    float ax = 0.f, ay = 0.f;
    #pragma unroll
    for (int s = 0; s < SS; ++s) {
      int j = __shfl(cidx, c * SS + s + (half << 5));  // this half's indices
      float2 v = *(const float2*)(feat + (size_t)j * DD + 2 * hl);
      ax = ax + v.x;                       // sequential, ascending s
      ay = ay + v.y;
    }
    ax = ax * 0.125f;                      // /8 exact
    ay = ay * 0.125f;
    g.x = (c == 0) ? ax : fmaxf(g.x, ax);  // max over c, ascending
    g.y = (c == 0) ? ay : fmaxf(g.y, ay);
  }
  float2 h1a = make_float2(fmaxf(x.x, 0.f), fmaxf(x.y, 0.f));
  float2 h1b = make_float2(fmaxf(g.x, 0.f), fmaxf(g.y, 0.f));
  size_t base = (size_t)n * OUTW + 2 * hl;
  *(float2*)(out + base) = h1a;
  *(float2*)(out + base + 64) = h1b;
  *(float2*)(out + base + 128) = h1a;      // h2 first half == h1 (relu(h1)=h1)
  *(float2*)(out + base + 192) = h1b;
}

// ---------------- Layer 2: 1-step KMeans + scatter-mean + maxpool -----------
// one wave per block. Golden bit-order preserved (W16 chained-FMA dot + W16
// pairwise c2, halves-tree reduces; sequential means; IEEE div; first-min
// argmin). Aggregate: values from LDS at point of use (no long-lived register
// cache — preserves dot-phase LDS pipelining, r17 lesson); selector bits from
// the wave-uniform ballot masks via SCALAR pipe. Bitwise identical to golden.
// k2 is gather-bandwidth-bound: time == FETCH/3.7TB/s (r14/r18/r19 evidence).
__global__ __launch_bounds__(64) void sdgnn_k2(
    const int* __restrict__ comm, const int* __restrict__ neigh,
    float* __restrict__ out, int N) {
  #pragma clang fp contract(off)
  __shared__ __align__(16) float L[(MM + CC) * LDST];
  const int lane = threadIdx.x;
  const int n = blockIdx.x;

  const int cidx = comm[(size_t)n * (CC * SS) + (lane & 31)];
  const int nidx = neigh[(size_t)n * MM + (lane & 15)];

  // stage neighbor h1 rows to LDS
  #pragma unroll
  for (int m = 0; m < MM; ++m) {
    int j = __shfl(nidx, m);
    float2 v = *(const float2*)(out + (size_t)j * OUTW + 2 * lane);
    *(float2*)(L + m * LDST + 2 * lane) = v;
  }
  // init centers = mean of 8 member h1 rows: sequential ascending-s adds
  float2 ctr[CC];
  #pragma unroll
  for (int c = 0; c < CC; ++c) {
    float ax = 0.f, ay = 0.f;
    #pragma unroll
    for (int s = 0; s < SS; ++s) {
      int j = __shfl(cidx, c * SS + s);
      float2 v = *(const float2*)(out + (size_t)j * OUTW + 2 * lane);
      ax = ax + v.x;
      ay = ay + v.y;
    }
    ctr[c].x = ax * 0.125f;
    ctr[c].y = ay * 0.125f;
    *(float2*)(L + (MM + c) * LDST + 2 * lane) = ctr[c];
  }
  __syncthreads();

  const int mm = lane >> 2, cc = lane & 3;
  const float4* nrow4 = (const float4*)(L + mm * LDST);
  const float4* crow4 = (const float4*)(L + (MM + cc) * LDST);
  const float* c2row = L + (MM + (lane >> 4)) * LDST;  // c2 row (c = lane>>4)
  const int Lc = lane & 15;

  // c2 cooperative: lane (c,L) computes S[L]; shfl_xor strides 8,4,2,1 equal
  // the halves-tree bitwise (IEEE add commutes).
  auto compute_c2 = [&]() -> float {
    #pragma clang fp contract(off)
    float a0 = c2row[0*16+Lc], a1 = c2row[1*16+Lc], a2 = c2row[2*16+Lc], a3 = c2row[3*16+Lc];
    float a4 = c2row[4*16+Lc], a5 = c2row[5*16+Lc], a6 = c2row[6*16+Lc], a7 = c2row[7*16+Lc];
    float s = ((a0*a0 + a1*a1) + (a2*a2 + a3*a3)) + ((a4*a4 + a5*a5) + (a6*a6 + a7*a7));
    s = s + __shfl_xor(s, 8);
    s = s + __shfl_xor(s, 4);
    s = s + __shfl_xor(s, 2);
    s = s + __shfl_xor(s, 1);
    return __shfl(s, cc << 4);   // c2 of this lane's cluster cc
  };

  // dot: W16 chained-FMA per model-lane, ascending k, halves-tree reduce.
  auto assign_lbl = [&]() -> int {
    #pragma clang fp contract(off)
    float c2 = compute_c2();
    float S[16];
    #pragma unroll
    for (int j = 0; j < 4; ++j) {
      float sx = 0.f, sy = 0.f, sz = 0.f, sw = 0.f;
      #pragma unroll
      for (int k = 0; k < 8; ++k) {
        float4 a = nrow4[k*4+j], b = crow4[k*4+j];
        sx = fmaf(a.x, b.x, sx);
        sy = fmaf(a.y, b.y, sy);
        sz = fmaf(a.z, b.z, sz);
        sw = fmaf(a.w, b.w, sw);
      }
      S[4*j+0] = sx; S[4*j+1] = sy; S[4*j+2] = sz; S[4*j+3] = sw;
    }
    float A0 = S[0] + S[8],  A1 = S[1] + S[9],  A2 = S[2] + S[10], A3 = S[3] + S[11];
    float A4 = S[4] + S[12], A5 = S[5] + S[13], A6 = S[6] + S[14], A7 = S[7] + S[15];
    float B0 = A0 + A4, B1 = A1 + A5, B2 = A2 + A6, B3 = A3 + A7;
    float C0 = B0 + B2, C1 = B1 + B3;
    float dot = C0 + C1;

    float bd = c2 - 2.f * dot;   // 2*dot exact; one rounded subtract
    int bc = cc;
    #pragma unroll
    for (int off = 1; off <= 2; off <<= 1) {
      float od = __shfl_xor(bd, off);
      int oc = __shfl_xor(bc, off);
      if (od < bd || (od == bd && oc < bc)) { bd = od; bc = oc; }
    }
    return bc;  // label of neighbor mm on all 4 group lanes
  };

  // scatter-sum by label, ascending m, values from LDS; selector from the
  // wave-uniform ballot masks (scalar pipe: s_lshr/s_and -> SGPR 0/1 float
  // operand of v_fmac). No v_cmp/cndmask, no label shuffles.
  auto aggregate = [&](int bc, float2 acc[CC], float cnt[CC]) {
    #pragma clang fp contract(off)
    unsigned long long msk[CC];
    #pragma unroll
    for (int c = 0; c < CC; ++c) {
      msk[c] = __ballot(bc == c);                           // wave-uniform SGPR
      acc[c].x = 0.f; acc[c].y = 0.f;
      cnt[c] = (float)__popcll(msk[c] & 0x1111111111111111ULL);  // lanes 4m
    }
    #pragma unroll
    for (int m = 0; m < MM; ++m) {
      float2 v = *(const float2*)(L + m * LDST + 2 * lane);
      #pragma unroll
      for (int c = 0; c < CC; ++c) {
        float sel = __uint_as_float(
            (unsigned)((msk[c] >> (4 * m)) & 1ULL) * 0x3f800000u);  // scalar 0/1
        acc[c].x = fmaf(sel, v.x, acc[c].x);
        acc[c].y = fmaf(sel, v.y, acc[c].y);
      }
    }
  };

  // E-step on init centers, then M-step
  int lbl0 = assign_lbl();
  float2 a0[CC]; float c0[CC];
  aggregate(lbl0, a0, c0);
  float2 ctr1[CC];
  #pragma unroll
  for (int c = 0; c < CC; ++c) {
    float den = fmaxf(c0[c], 1.f);       // maximum(cnt,1.0)
    float mx = a0[c].x / den;            // IEEE f32 divide
    float my = a0[c].y / den;
    ctr1[c].x = (c0[c] > 0.f) ? mx : ctr[c].x;  // where(cnt>0, mean, center)
    ctr1[c].y = (c0[c] > 0.f) ? my : ctr[c].y;
  }
  __syncthreads();  // WAR on center rows (1 wave: cheap)
  #pragma unroll
  for (int c = 0; c < CC; ++c)
    *(float2*)(L + (MM + c) * LDST + 2 * lane) = ctr1[c];
  __syncthreads();

  // final E-step + scatter-mean (empty -> 0) + maxpool + relu
  int lbl1 = assign_lbl();
  float2 a1[CC]; float c1n[CC];
  aggregate(lbl1, a1, c1n);
  float rx = 0.f, ry = 0.f;
  #pragma unroll
  for (int c = 0; c < CC; ++c) {
    float den = fmaxf(c1n[c], 1.f);
    float gx = a1[c].x / den;            // empty: 0/1 = +0
    float gy = a1[c].y / den;
    rx = (c == 0) ? gx : fmaxf(rx, gx);  // max over c, ascending
    ry = (c == 0) ? gy : fmaxf(ry, gy);
  }
  size_t base = (size_t)n * OUTW + 256 + 2 * lane;
  float2 res;
  res.x = fmaxf(rx, 0.f);
  res.y = fmaxf(ry, 0.f);
  *(float2*)(out + base) = res;
}

extern "C" void kernel_launch(void* const* d_in, const int* in_sizes, int n_in,
                              void* d_out, int out_size, void* d_ws, size_t ws_size,
                              hipStream_t stream) {
  const float* feat = (const float*)d_in[0];
  const int* comm = (const int*)d_in[1];
  const int* neigh = (const int*)d_in[2];
  float* out = (float*)d_out;
  const int N = in_sizes[0] / DD;

  int blocks1 = (N + 7) / 8;   // 4 waves/block, 2 nodes per wave
  sdgnn_k1<<<blocks1, 256, 0, stream>>>(feat, comm, out, N);
  sdgnn_k2<<<N, 64, 0, stream>>>(comm, neigh, out, N);  // 1 wave per node
}